// Round 6
// baseline (80.735 us; speedup 1.0000x reference)
//
#include <hip/hip_runtime.h>
#include <cmath>

#define T_SEQ 4096
#define D_MODEL 1024
#define EPS 1e-6f
#define ROWS 40   // padded shorts per transposed LDS row (80 B: 16B-aligned, bank-spread)
#define CHUNKS 32 // chunks per head; 64*32 = 2048 blocks = 8 blocks/CU (100% occupancy)

typedef __attribute__((ext_vector_type(8))) short bf16x8;
typedef __attribute__((ext_vector_type(4))) float f32x4;

__device__ __forceinline__ float elu1(float x) { return x > 0.f ? x + 1.f : __expf(x); }

// float -> bf16 bits, round-to-nearest-even
__device__ __forceinline__ unsigned f2bf_u(float f) {
    union { float f; unsigned u; } v; v.f = f;
    unsigned r = v.u + 0x7fffu + ((v.u >> 16) & 1u);
    return r >> 16;
}
__device__ __forceinline__ short f2bf(float f) { return (short)f2bf_u(f); }
__device__ __forceinline__ unsigned packbf(float lo, float hi) {
    return f2bf_u(lo) | (f2bf_u(hi) << 16);
}
// 4-pair-group XOR swizzle key per row e: spreads banks for both writes and reads
__device__ __forceinline__ int swz(int e) { return ((e >> 2) ^ (e >> 4)) & 3; }

// ---------------------------------------------------------------------------
// Kernel A: partial context per (head, chunk) via MFMA, transposed-LDS staged.
// grid = 64 heads * 32 chunks (2048 blocks = 8/CU), block = 256 (4 waves).
// LDS holds K' and V TRANSPOSED: row = feature (e or d), 32 s-values per row
// (bf16, pair-packed), row stride 40 shorts. A/B frags = one ds_read_b128 of
// 8 consecutive s at fixed feature = exact MFMA frag layout. Wave (eh,dh)
// owns ctx quadrant [32eh..+32][32dh..+32]; no cross-wave reduction.
// ksum via ones-column B tile on dh==0 waves.
// ---------------------------------------------------------------------------
__global__ __launch_bounds__(256) void ctx_partial(const float* __restrict__ K,
                                                   const float* __restrict__ V,
                                                   float* __restrict__ partial) {
    __shared__ __align__(16) short sT[2][2][64 * ROWS];  // [buf][K=0,V=1][e][s]

    const int head = blockIdx.x >> 5, chunk = blockIdx.x & 31;
    const int b = head >> 4, h = head & 15;
    const int tid = threadIdx.x;
    const int wave = tid >> 6, lane = tid & 63;
    const int eh = wave >> 1, dh = wave & 1;
    const int g = lane >> 4, r = lane & 15;

    const size_t base = (size_t)b * T_SEQ * D_MODEL + (size_t)h * 64;
    const int s0 = chunk * 128;

    // staging map: thread owns s-pair u (s = 2u, 2u+1), e columns e0..e0+3
    const int u  = tid >> 4;
    const int e0 = 4 * (tid & 15);

    f32x4 acc[2][2], accs[2];
#pragma unroll
    for (int i = 0; i < 2; ++i)
#pragma unroll
        for (int q = 0; q < 4; ++q) { accs[i][q] = 0.f; acc[i][0][q] = 0.f; acc[i][1][q] = 0.f; }

    bf16x8 ones;
    const short ob = (r == 0) ? (short)0x3F80 : (short)0;
#pragma unroll
    for (int j = 0; j < 8; ++j) ones[j] = ob;

    float kr[2][4], vr[2][4];
    auto load_tile = [&](int t) {
        const float* Kp = K + base + (size_t)(s0 + 32 * t + 2 * u) * D_MODEL + e0;
        const float* Vp = V + base + (size_t)(s0 + 32 * t + 2 * u) * D_MODEL + e0;
        float4 ka = *(const float4*)Kp;
        float4 kb = *(const float4*)(Kp + D_MODEL);
        float4 va = *(const float4*)Vp;
        float4 vb = *(const float4*)(Vp + D_MODEL);
        kr[0][0] = ka.x; kr[0][1] = ka.y; kr[0][2] = ka.z; kr[0][3] = ka.w;
        kr[1][0] = kb.x; kr[1][1] = kb.y; kr[1][2] = kb.z; kr[1][3] = kb.w;
        vr[0][0] = va.x; vr[0][1] = va.y; vr[0][2] = va.z; vr[0][3] = va.w;
        vr[1][0] = vb.x; vr[1][1] = vb.y; vr[1][2] = vb.z; vr[1][3] = vb.w;
    };
    auto store_tile = [&](int buf) {
        short* tk = &sT[buf][0][0];
        short* tv = &sT[buf][1][0];
#pragma unroll
        for (int i = 0; i < 4; ++i) {
            const int e = e0 + i;
            const int off = ROWS * e + 8 * ((u >> 2) ^ swz(e)) + 2 * (u & 3);
            *(unsigned*)&tk[off] = packbf(elu1(kr[0][i]), elu1(kr[1][i]));
            *(unsigned*)&tv[off] = packbf(vr[0][i], vr[1][i]);
        }
    };
    auto compute = [&](int buf) {
        const short* tk = &sT[buf][0][0];
        const short* tv = &sT[buf][1][0];
        bf16x8 a[2], bb[2];
#pragma unroll
        for (int mi = 0; mi < 2; ++mi) {
            const int e = 32 * eh + 16 * mi + r;
            a[mi] = *(const bf16x8*)&tk[ROWS * e + 8 * (g ^ swz(e))];
        }
#pragma unroll
        for (int ni = 0; ni < 2; ++ni) {
            const int d = 32 * dh + 16 * ni + r;
            bb[ni] = *(const bf16x8*)&tv[ROWS * d + 8 * (g ^ swz(d))];
        }
#pragma unroll
        for (int mi = 0; mi < 2; ++mi) {
#pragma unroll
            for (int ni = 0; ni < 2; ++ni)
                acc[mi][ni] = __builtin_amdgcn_mfma_f32_16x16x32_bf16(a[mi], bb[ni], acc[mi][ni], 0, 0, 0);
            if (dh == 0)
                accs[mi] = __builtin_amdgcn_mfma_f32_16x16x32_bf16(a[mi], ones, accs[mi], 0, 0, 0);
        }
    };

    load_tile(0);
    store_tile(0);
    __syncthreads();
#pragma unroll 1
    for (int t = 0; t < 4; ++t) {
        if (t < 3) load_tile(t + 1);      // issue next-tile global loads early
        compute(t & 1);
        if (t < 3) store_tile((t + 1) & 1);
        __syncthreads();
    }

    float* outp = partial + (size_t)blockIdx.x * 4160;
#pragma unroll
    for (int mi = 0; mi < 2; ++mi) {
        const int e_base = (2 * eh + mi) * 16 + 4 * g;
#pragma unroll
        for (int ni = 0; ni < 2; ++ni) {
            const int d_loc = (2 * dh + ni) * 16 + r;
#pragma unroll
            for (int q = 0; q < 4; ++q)
                outp[(e_base + q) * 64 + d_loc] = acc[mi][ni][q];
        }
        if (dh == 0 && r == 0) {
#pragma unroll
            for (int q = 0; q < 4; ++q)
                outp[4096 + e_base + q] = accs[mi][q];
        }
    }
}

// ---------------------------------------------------------------------------
// Kernel A2: reduce 32 chunk partials -> final ctx per head.
// grid = 256 (64 heads x 4 slices of 1040 elements).
// ---------------------------------------------------------------------------
__global__ __launch_bounds__(256) void ctx_reduce(const float* __restrict__ partial,
                                                  float* __restrict__ ctx) {
    const int head = blockIdx.x >> 2, part = blockIdx.x & 3;
    const int lo = part * 1040, hi = lo + 1040;
    for (int idx = lo + threadIdx.x; idx < hi; idx += 256) {
        float s = 0.f;
#pragma unroll
        for (int c = 0; c < CHUNKS; ++c)
            s += partial[((size_t)head * CHUNKS + c) * 4160 + idx];
        ctx[(size_t)head * 4160 + idx] = s;
    }
}

// ---------------------------------------------------------------------------
// Kernel B: out = (Q' ctx) / (Q' ksum + eps) via MFMA. (round-2 passing code)
// grid = 64 heads * 16 row-chunks, block = 256 (4 waves x 64 rows).
// ---------------------------------------------------------------------------
__global__ __launch_bounds__(256) void attn_out(const float* __restrict__ Q,
                                                const float* __restrict__ ctx,
                                                float* __restrict__ out) {
    const int head = blockIdx.x >> 4, nb = blockIdx.x & 15;
    const int b = head >> 4, h = head & 15;
    const int tid = threadIdx.x, wave = tid >> 6, lane = tid & 63;
    const int g = lane >> 4, r = lane & 15;
    const float* C = ctx + (size_t)head * 4160;

    bf16x8 bfr[2][5];
#pragma unroll
    for (int kt = 0; kt < 2; ++kt)
#pragma unroll
        for (int j = 0; j < 8; ++j) {
            const int e = kt * 32 + 8 * g + j;
#pragma unroll
            for (int n = 0; n < 4; ++n) bfr[kt][n][j] = f2bf(C[e * 64 + 16 * n + r]);
            bfr[kt][4][j] = (r == 0) ? f2bf(C[4096 + e]) : (short)0;
        }

    const int n0 = nb * 256 + wave * 64;
    const float* qbase = Q + ((size_t)b * T_SEQ + n0) * D_MODEL + (size_t)h * 64;

    f32x4 acc[4][5];
#pragma unroll
    for (int m = 0; m < 4; ++m)
#pragma unroll
        for (int n = 0; n < 5; ++n)
#pragma unroll
            for (int q = 0; q < 4; ++q) acc[m][n][q] = 0.f;

#pragma unroll
    for (int kt = 0; kt < 2; ++kt)
#pragma unroll
        for (int m = 0; m < 4; ++m) {
            const float* qp = qbase + (size_t)(16 * m + r) * D_MODEL + kt * 32 + 8 * g;
            const float4 q1 = *(const float4*)qp;
            const float4 q2 = *(const float4*)(qp + 4);
            bf16x8 a;
            a[0] = f2bf(elu1(q1.x)); a[1] = f2bf(elu1(q1.y));
            a[2] = f2bf(elu1(q1.z)); a[3] = f2bf(elu1(q1.w));
            a[4] = f2bf(elu1(q2.x)); a[5] = f2bf(elu1(q2.y));
            a[6] = f2bf(elu1(q2.z)); a[7] = f2bf(elu1(q2.w));
#pragma unroll
            for (int n = 0; n < 5; ++n)
                acc[m][n] = __builtin_amdgcn_mfma_f32_16x16x32_bf16(a, bfr[kt][n], acc[m][n], 0, 0, 0);
        }

#pragma unroll
    for (int m = 0; m < 4; ++m) {
        float dinv[4];
#pragma unroll
        for (int q = 0; q < 4; ++q)
            dinv[q] = 1.f / (__shfl(acc[m][4][q], lane & 48) + EPS);
#pragma unroll
        for (int q = 0; q < 4; ++q) {
            float* op = out + ((size_t)b * T_SEQ + n0 + 16 * m + 4 * g + q) * D_MODEL
                        + (size_t)h * 64 + r;
#pragma unroll
            for (int n = 0; n < 4; ++n) op[16 * n] = acc[m][n][q] * dinv[q];
        }
    }
}

extern "C" void kernel_launch(void* const* d_in, const int* in_sizes, int n_in,
                              void* d_out, int out_size, void* d_ws, size_t ws_size,
                              hipStream_t stream) {
    const float* Q = (const float*)d_in[0];
    const float* K = (const float*)d_in[1];
    const float* V = (const float*)d_in[2];
    float* out = (float*)d_out;
    float* ws  = (float*)d_ws;

    // Partials (2048 * 4160 floats = 34 MB) live in d_out-as-scratch (67 MB);
    // consumed by ctx_reduce, then d_out is fully overwritten by attn_out.
    float* partial = out;
    float* ctx     = ws;                               // 64*4160 floats (~1.1 MB)

    hipLaunchKernelGGL(ctx_partial, dim3(64 * CHUNKS), dim3(256), 0, stream, K, V, partial);
    hipLaunchKernelGGL(ctx_reduce,  dim3(256),         dim3(256), 0, stream, partial, ctx);
    hipLaunchKernelGGL(attn_out,    dim3(1024),        dim3(256), 0, stream, Q, ctx, out);
}

// Round 7
// 71.161 us; speedup vs baseline: 1.1345x; 1.1345x over previous
//
#include <hip/hip_runtime.h>
#include <cmath>

#define T_SEQ 4096
#define D_MODEL 1024
#define EPS 1e-6f
#define CHUNKS 16

typedef __attribute__((ext_vector_type(8))) short bf16x8;
typedef __attribute__((ext_vector_type(4))) float f32x4;

__device__ __forceinline__ float elu1(float x) { return x > 0.f ? x + 1.f : __expf(x); }

// float -> bf16 bits, round-to-nearest-even
__device__ __forceinline__ unsigned f2bf_u(float f) {
    union { float f; unsigned u; } v; v.f = f;
    unsigned r = v.u + 0x7fffu + ((v.u >> 16) & 1u);
    return r >> 16;
}
__device__ __forceinline__ short f2bf(float f) { return (short)f2bf_u(f); }
__device__ __forceinline__ unsigned packbf(float lo, float hi) {
    return f2bf_u(lo) | (f2bf_u(hi) << 16);
}
// 4-octet XOR swizzle key per feature-row (R5-proven)
__device__ __forceinline__ int swz(int e) { return ((e >> 2) ^ (e >> 4)) & 3; }

// ---------------------------------------------------------------------------
// Kernel A: fused 4-head partial-context blocks.
// grid = 256 (4 b x 4 head-quads x 16 chunks), 1024 threads (16 waves), 80KB LDS.
// Staging: wave u stages rows {2u,2u+1}; one wave-instr = 64 lanes x float4 =
// 1 KB CONTIGUOUS global read (covers 4 heads' columns at once). Each K/V byte
// is read exactly once chip-wide.
// LDS: per (head, mat) transposed region [64 feat][40 shorts] (R5 layout),
// octet o = (u>>2)^swz(e)^head, slot = (u&3)^head — head-XOR spreads banks
// across the 4 head regions; K and V share the s-permutation (MFMA-exact).
// Compute: wave (hh, quadrant) does R5's 2x2-tile MFMA + ones-column ksum.
// Partials: register-order f32x4 blob (dense 1-KB stores); reduce decodes.
// ---------------------------------------------------------------------------
__global__ __launch_bounds__(1024) void ctx_fused(const float* __restrict__ K,
                                                  const float* __restrict__ V,
                                                  float* __restrict__ partial) {
    __shared__ __align__(16) short sT[2][4][2][64 * 40];  // [buf][head][mat][e][s]

    const int bb = blockIdx.x >> 6;
    const int hq = (blockIdx.x >> 4) & 3;
    const int ch = blockIdx.x & 15;
    const int tid = threadIdx.x;
    const int wave = tid >> 6, lane = tid & 63;
    // compute roles: head hh, quadrant (eh, dh)
    const int hh = wave >> 2, qd = wave & 3, eh = qd >> 1, dh = qd & 1;
    const int g = lane >> 4, r = lane & 15;
    // staging roles: wave = s-pair u, lane = col granule c6
    const int u = wave, c6 = lane;
    const int hw = c6 >> 4;            // head of staged columns
    const int eq = c6 & 15;            // e-quad within that head

    const size_t base = (size_t)bb * T_SEQ * D_MODEL;
    const int s0 = ch * 256;
    const int colb = hq * 256;

    f32x4 acc[2][2], accs[2];
#pragma unroll
    for (int i = 0; i < 2; ++i)
#pragma unroll
        for (int q = 0; q < 4; ++q) { accs[i][q] = 0.f; acc[i][0][q] = 0.f; acc[i][1][q] = 0.f; }

    bf16x8 ones;
    const short ob = (r == 0) ? (short)0x3F80 : (short)0;
#pragma unroll
    for (int j = 0; j < 8; ++j) ones[j] = ob;

    float4 kf[2], vf[2];
    auto load_tile = [&](int kt) {
        const float* Kp = K + base + (size_t)(s0 + 32 * kt + 2 * u) * D_MODEL + colb + 4 * c6;
        const float* Vp = V + base + (size_t)(s0 + 32 * kt + 2 * u) * D_MODEL + colb + 4 * c6;
        kf[0] = *(const float4*)Kp;
        kf[1] = *(const float4*)(Kp + D_MODEL);
        vf[0] = *(const float4*)Vp;
        vf[1] = *(const float4*)(Vp + D_MODEL);
    };
    auto store_tile = [&](int buf) {
        short* tk = &sT[buf][hw][0][0];
        short* tv = &sT[buf][hw][1][0];
        const float* k0 = (const float*)&kf[0];
        const float* k1 = (const float*)&kf[1];
        const float* v0 = (const float*)&vf[0];
        const float* v1 = (const float*)&vf[1];
        const int sl2 = 2 * ((u & 3) ^ (hw & 3));
#pragma unroll
        for (int i = 0; i < 4; ++i) {
            const int e = 4 * eq + i;
            const int off = e * 40 + 8 * ((u >> 2) ^ swz(e) ^ (hw & 3)) + sl2;
            *(unsigned*)&tk[off] = packbf(elu1(k0[i]), elu1(k1[i]));
            *(unsigned*)&tv[off] = packbf(v0[i], v1[i]);
        }
    };
    auto compute = [&](int buf) {
        const short* tk = &sT[buf][hh][0][0];
        const short* tv = &sT[buf][hh][1][0];
        const int h3 = hh & 3;
        bf16x8 a[2], bv[2];
#pragma unroll
        for (int mi = 0; mi < 2; ++mi) {
            const int e = 32 * eh + 16 * mi + r;
            a[mi] = *(const bf16x8*)&tk[e * 40 + 8 * (g ^ swz(e) ^ h3)];
        }
#pragma unroll
        for (int ni = 0; ni < 2; ++ni) {
            const int d = 32 * dh + 16 * ni + r;
            bv[ni] = *(const bf16x8*)&tv[d * 40 + 8 * (g ^ swz(d) ^ h3)];
        }
#pragma unroll
        for (int mi = 0; mi < 2; ++mi) {
#pragma unroll
            for (int ni = 0; ni < 2; ++ni)
                acc[mi][ni] = __builtin_amdgcn_mfma_f32_16x16x32_bf16(a[mi], bv[ni], acc[mi][ni], 0, 0, 0);
            if (dh == 0)
                accs[mi] = __builtin_amdgcn_mfma_f32_16x16x32_bf16(a[mi], ones, accs[mi], 0, 0, 0);
        }
    };

    load_tile(0);
    store_tile(0);
    __syncthreads();
#pragma unroll 1
    for (int t = 0; t < 8; ++t) {
        if (t < 7) load_tile(t + 1);      // issue next-tile global loads early
        compute(t & 1);
        if (t < 7) store_tile((t + 1) & 1);
        __syncthreads();
    }

    // register-order partial blob: [qd][mi*2+ni][lane][4] + ksum tail (e-order)
    float* slab = partial + ((size_t)((bb * 16 + hq * 4 + hh) * CHUNKS + ch)) * 4160;
#pragma unroll
    for (int mi = 0; mi < 2; ++mi)
#pragma unroll
        for (int ni = 0; ni < 2; ++ni)
            *(f32x4*)&slab[qd * 1024 + (mi * 2 + ni) * 256 + lane * 4] = acc[mi][ni];
    if (dh == 0 && r == 0) {
#pragma unroll
        for (int mi = 0; mi < 2; ++mi)
#pragma unroll
            for (int q = 0; q < 4; ++q)
                slab[4096 + 32 * eh + 16 * mi + 4 * g + q] = accs[mi][q];
    }
}

// ---------------------------------------------------------------------------
// Kernel A2: sum 16 chunk blobs -> canonical ctx. grid = 256 (64 head x 4).
// Coalesced float4 reads of the blob; scatter 4B writes to ctx (L2-resident).
// ---------------------------------------------------------------------------
__global__ __launch_bounds__(256) void ctx_reduce(const float* __restrict__ partial,
                                                  float* __restrict__ ctx) {
    const int head = blockIdx.x >> 2, part = blockIdx.x & 3;
    const float* pbase = partial + (size_t)head * CHUNKS * 4160;
    float* cbase = ctx + (size_t)head * 4160;
    const int lo = part * 260;
    for (int i4 = lo + threadIdx.x; i4 < lo + 260; i4 += 256) {
        f32x4 s;
#pragma unroll
        for (int k = 0; k < 4; ++k) s[k] = 0.f;
#pragma unroll
        for (int c = 0; c < CHUNKS; ++c) {
            const f32x4 v = *(const f32x4*)&pbase[(size_t)c * 4160 + i4 * 4];
#pragma unroll
            for (int k = 0; k < 4; ++k) s[k] += v[k];
        }
        const int f0 = i4 * 4;
        if (f0 < 4096) {
#pragma unroll
            for (int k = 0; k < 4; ++k) {
                const int f = f0 + k;
                const int qd = f >> 10, t2 = (f >> 8) & 3, ln = (f >> 2) & 63, q = f & 3;
                const int e = 32 * (qd >> 1) + 16 * (t2 >> 1) + 4 * (ln >> 4) + q;
                const int d = 32 * (qd & 1) + 16 * (t2 & 1) + (ln & 15);
                cbase[e * 64 + d] = s[k];
            }
        } else {
#pragma unroll
            for (int k = 0; k < 4; ++k) cbase[f0 + k] = s[k];   // ksum tail, e-order
        }
    }
}

// ---------------------------------------------------------------------------
// Kernel B: out = (Q' ctx) / (Q' ksum + eps) via MFMA. (proven, unchanged)
// grid = 64 heads * 16 row-chunks, block = 256 (4 waves x 64 rows).
// ---------------------------------------------------------------------------
__global__ __launch_bounds__(256) void attn_out(const float* __restrict__ Q,
                                                const float* __restrict__ ctx,
                                                float* __restrict__ out) {
    const int head = blockIdx.x >> 4, nb = blockIdx.x & 15;
    const int b = head >> 4, h = head & 15;
    const int tid = threadIdx.x, wave = tid >> 6, lane = tid & 63;
    const int g = lane >> 4, r = lane & 15;
    const float* C = ctx + (size_t)head * 4160;

    bf16x8 bfr[2][5];
#pragma unroll
    for (int kt = 0; kt < 2; ++kt)
#pragma unroll
        for (int j = 0; j < 8; ++j) {
            const int e = kt * 32 + 8 * g + j;
#pragma unroll
            for (int n = 0; n < 4; ++n) bfr[kt][n][j] = f2bf(C[e * 64 + 16 * n + r]);
            bfr[kt][4][j] = (r == 0) ? f2bf(C[4096 + e]) : (short)0;
        }

    const int n0 = nb * 256 + wave * 64;
    const float* qbase = Q + ((size_t)b * T_SEQ + n0) * D_MODEL + (size_t)h * 64;

    f32x4 acc[4][5];
#pragma unroll
    for (int m = 0; m < 4; ++m)
#pragma unroll
        for (int n = 0; n < 5; ++n)
#pragma unroll
            for (int q = 0; q < 4; ++q) acc[m][n][q] = 0.f;

#pragma unroll
    for (int kt = 0; kt < 2; ++kt)
#pragma unroll
        for (int m = 0; m < 4; ++m) {
            const float* qp = qbase + (size_t)(16 * m + r) * D_MODEL + kt * 32 + 8 * g;
            const float4 q1 = *(const float4*)qp;
            const float4 q2 = *(const float4*)(qp + 4);
            bf16x8 a;
            a[0] = f2bf(elu1(q1.x)); a[1] = f2bf(elu1(q1.y));
            a[2] = f2bf(elu1(q1.z)); a[3] = f2bf(elu1(q1.w));
            a[4] = f2bf(elu1(q2.x)); a[5] = f2bf(elu1(q2.y));
            a[6] = f2bf(elu1(q2.z)); a[7] = f2bf(elu1(q2.w));
#pragma unroll
            for (int n = 0; n < 5; ++n)
                acc[m][n] = __builtin_amdgcn_mfma_f32_16x16x32_bf16(a, bfr[kt][n], acc[m][n], 0, 0, 0);
        }

#pragma unroll
    for (int m = 0; m < 4; ++m) {
        float dinv[4];
#pragma unroll
        for (int q = 0; q < 4; ++q)
            dinv[q] = 1.f / (__shfl(acc[m][4][q], lane & 48) + EPS);
#pragma unroll
        for (int q = 0; q < 4; ++q) {
            float* op = out + ((size_t)b * T_SEQ + n0 + 16 * m + 4 * g + q) * D_MODEL
                        + (size_t)h * 64 + r;
#pragma unroll
            for (int n = 0; n < 4; ++n) op[16 * n] = acc[m][n][q] * dinv[q];
        }
    }
}

extern "C" void kernel_launch(void* const* d_in, const int* in_sizes, int n_in,
                              void* d_out, int out_size, void* d_ws, size_t ws_size,
                              hipStream_t stream) {
    const float* Q = (const float*)d_in[0];
    const float* K = (const float*)d_in[1];
    const float* V = (const float*)d_in[2];
    float* out = (float*)d_out;
    float* ws  = (float*)d_ws;

    // Partials (64*16*4160 floats = 17 MB) live in d_out-as-scratch; consumed
    // by ctx_reduce, then d_out is fully overwritten by attn_out.
    float* partial = out;
    float* ctx     = ws;                               // 64*4160 floats (~1.1 MB)

    hipLaunchKernelGGL(ctx_fused,  dim3(256),  dim3(1024), 0, stream, K, V, partial);
    hipLaunchKernelGGL(ctx_reduce, dim3(256),  dim3(256),  0, stream, partial, ctx);
    hipLaunchKernelGGL(attn_out,   dim3(1024), dim3(256),  0, stream, Q, ctx, out);
}

// Round 8
// 58.437 us; speedup vs baseline: 1.3816x; 1.2177x over previous
//
#include <hip/hip_runtime.h>
#include <cmath>

#define T_SEQ 4096
#define D_MODEL 1024
#define EPS 1e-6f
#define CHUNKS 16

typedef __attribute__((ext_vector_type(8))) short bf16x8;
typedef __attribute__((ext_vector_type(4))) float f32x4;

__device__ __forceinline__ float elu1(float x) { return x > 0.f ? x + 1.f : __expf(x); }

// float -> bf16 bits, round-to-nearest-even
__device__ __forceinline__ unsigned f2bf_u(float f) {
    union { float f; unsigned u; } v; v.f = f;
    unsigned r = v.u + 0x7fffu + ((v.u >> 16) & 1u);
    return r >> 16;
}
__device__ __forceinline__ short f2bf(float f) { return (short)f2bf_u(f); }
__device__ __forceinline__ unsigned packbf(float lo, float hi) {
    return f2bf_u(lo) | (f2bf_u(hi) << 16);
}
// pack 2 f32 -> 2 bf16 (RNE), dst.lo = first arg (proven in R5-R7 store_tile)
__device__ __forceinline__ unsigned cvt_pk_bf16(float lo, float hi) {
    unsigned r;
    asm("v_cvt_pk_bf16_f32 %0, %1, %2" : "=v"(r) : "v"(lo), "v"(hi));
    return r;
}
// 4-octet XOR swizzle key per feature-row (R5-proven)
__device__ __forceinline__ int swz(int e) { return ((e >> 2) ^ (e >> 4)) & 3; }

// ---------------------------------------------------------------------------
// Kernel A: fused 4-head partial-context blocks. (R7-verbatim, proven)
// grid = 256 (4 b x 4 head-quads x 16 chunks), 1024 threads, 80KB LDS.
// ---------------------------------------------------------------------------
__global__ __launch_bounds__(1024) void ctx_fused(const float* __restrict__ K,
                                                  const float* __restrict__ V,
                                                  float* __restrict__ partial) {
    __shared__ __align__(16) short sT[2][4][2][64 * 40];  // [buf][head][mat][e][s]

    const int bb = blockIdx.x >> 6;
    const int hq = (blockIdx.x >> 4) & 3;
    const int ch = blockIdx.x & 15;
    const int tid = threadIdx.x;
    const int wave = tid >> 6, lane = tid & 63;
    const int hh = wave >> 2, qd = wave & 3, eh = qd >> 1, dh = qd & 1;
    const int g = lane >> 4, r = lane & 15;
    const int u = wave, c6 = lane;
    const int hw = c6 >> 4;
    const int eq = c6 & 15;

    const size_t base = (size_t)bb * T_SEQ * D_MODEL;
    const int s0 = ch * 256;
    const int colb = hq * 256;

    f32x4 acc[2][2], accs[2];
#pragma unroll
    for (int i = 0; i < 2; ++i)
#pragma unroll
        for (int q = 0; q < 4; ++q) { accs[i][q] = 0.f; acc[i][0][q] = 0.f; acc[i][1][q] = 0.f; }

    bf16x8 ones;
    const short ob = (r == 0) ? (short)0x3F80 : (short)0;
#pragma unroll
    for (int j = 0; j < 8; ++j) ones[j] = ob;

    float4 kf[2], vf[2];
    auto load_tile = [&](int kt) {
        const float* Kp = K + base + (size_t)(s0 + 32 * kt + 2 * u) * D_MODEL + colb + 4 * c6;
        const float* Vp = V + base + (size_t)(s0 + 32 * kt + 2 * u) * D_MODEL + colb + 4 * c6;
        kf[0] = *(const float4*)Kp;
        kf[1] = *(const float4*)(Kp + D_MODEL);
        vf[0] = *(const float4*)Vp;
        vf[1] = *(const float4*)(Vp + D_MODEL);
    };
    auto store_tile = [&](int buf) {
        short* tk = &sT[buf][hw][0][0];
        short* tv = &sT[buf][hw][1][0];
        const float* k0 = (const float*)&kf[0];
        const float* k1 = (const float*)&kf[1];
        const float* v0 = (const float*)&vf[0];
        const float* v1 = (const float*)&vf[1];
        const int sl2 = 2 * ((u & 3) ^ (hw & 3));
#pragma unroll
        for (int i = 0; i < 4; ++i) {
            const int e = 4 * eq + i;
            const int off = e * 40 + 8 * ((u >> 2) ^ swz(e) ^ (hw & 3)) + sl2;
            *(unsigned*)&tk[off] = packbf(elu1(k0[i]), elu1(k1[i]));
            *(unsigned*)&tv[off] = packbf(v0[i], v1[i]);
        }
    };
    auto compute = [&](int buf) {
        const short* tk = &sT[buf][hh][0][0];
        const short* tv = &sT[buf][hh][1][0];
        const int h3 = hh & 3;
        bf16x8 a[2], bv[2];
#pragma unroll
        for (int mi = 0; mi < 2; ++mi) {
            const int e = 32 * eh + 16 * mi + r;
            a[mi] = *(const bf16x8*)&tk[e * 40 + 8 * (g ^ swz(e) ^ h3)];
        }
#pragma unroll
        for (int ni = 0; ni < 2; ++ni) {
            const int d = 32 * dh + 16 * ni + r;
            bv[ni] = *(const bf16x8*)&tv[d * 40 + 8 * (g ^ swz(d) ^ h3)];
        }
#pragma unroll
        for (int mi = 0; mi < 2; ++mi) {
#pragma unroll
            for (int ni = 0; ni < 2; ++ni)
                acc[mi][ni] = __builtin_amdgcn_mfma_f32_16x16x32_bf16(a[mi], bv[ni], acc[mi][ni], 0, 0, 0);
            if (dh == 0)
                accs[mi] = __builtin_amdgcn_mfma_f32_16x16x32_bf16(a[mi], ones, accs[mi], 0, 0, 0);
        }
    };

    load_tile(0);
    store_tile(0);
    __syncthreads();
#pragma unroll 1
    for (int t = 0; t < 8; ++t) {
        if (t < 7) load_tile(t + 1);
        compute(t & 1);
        if (t < 7) store_tile((t + 1) & 1);
        __syncthreads();
    }

    float* slab = partial + ((size_t)((bb * 16 + hq * 4 + hh) * CHUNKS + ch)) * 4160;
#pragma unroll
    for (int mi = 0; mi < 2; ++mi)
#pragma unroll
        for (int ni = 0; ni < 2; ++ni)
            *(f32x4*)&slab[qd * 1024 + (mi * 2 + ni) * 256 + lane * 4] = acc[mi][ni];
    if (dh == 0 && r == 0) {
#pragma unroll
        for (int mi = 0; mi < 2; ++mi)
#pragma unroll
            for (int q = 0; q < 4; ++q)
                slab[4096 + 32 * eh + 16 * mi + 4 * g + q] = accs[mi][q];
    }
}

// ---------------------------------------------------------------------------
// Kernel A2: sum 16 chunk blobs -> TRANSPOSED bf16 context, fragment-ready.
// CT[d][e] = bf16(ctx[e][d]) for d<64; CT[64][e] = bf16(ksum[e]).
// Per head 4160 shorts (8.3 KB). grid = 256 (64 heads x 4 parts).
// ---------------------------------------------------------------------------
__global__ __launch_bounds__(256) void ctx_reduce(const float* __restrict__ partial,
                                                  ushort* __restrict__ ctxbf) {
    const int head = blockIdx.x >> 2, part = blockIdx.x & 3;
    const float* pbase = partial + (size_t)head * CHUNKS * 4160;
    ushort* cbase = ctxbf + (size_t)head * 4160;
    const int lo = part * 260;
    for (int i4 = lo + threadIdx.x; i4 < lo + 260; i4 += 256) {
        f32x4 s;
#pragma unroll
        for (int k = 0; k < 4; ++k) s[k] = 0.f;
#pragma unroll
        for (int c = 0; c < CHUNKS; ++c) {
            const f32x4 v = *(const f32x4*)&pbase[(size_t)c * 4160 + i4 * 4];
#pragma unroll
            for (int k = 0; k < 4; ++k) s[k] += v[k];
        }
        const int f0 = i4 * 4;
        if (f0 < 4096) {
#pragma unroll
            for (int k = 0; k < 4; ++k) {
                const int f = f0 + k;
                const int qd = f >> 10, t2 = (f >> 8) & 3, ln = (f >> 2) & 63, q = f & 3;
                const int e = 32 * (qd >> 1) + 16 * (t2 >> 1) + 4 * (ln >> 4) + q;
                const int d = 32 * (qd & 1) + 16 * (t2 & 1) + (ln & 15);
                cbase[d * 64 + e] = (ushort)f2bf(s[k]);
            }
        } else {
#pragma unroll
            for (int k = 0; k < 4; ++k) cbase[f0 + k] = (ushort)f2bf(s[k]);  // ksum row
        }
    }
}

// ---------------------------------------------------------------------------
// Kernel B: out = (Q' ctx) / (Q' ksum + eps) via MFMA.
// v2: fragments sourced as 10x b128 loads from frag-ready CT (L2-hot);
// Q conversion via v_cvt_pk_bf16_f32; launch_bounds(256,4) pins VGPR<=128.
// grid = 64 heads * 16 row-chunks, block = 256 (4 waves x 64 rows).
// ---------------------------------------------------------------------------
__global__ __launch_bounds__(256, 4) void attn_out(const float* __restrict__ Q,
                                                   const ushort* __restrict__ ctxbf,
                                                   float* __restrict__ out) {
    const int head = blockIdx.x >> 4, nb = blockIdx.x & 15;
    const int b = head >> 4, h = head & 15;
    const int tid = threadIdx.x, wave = tid >> 6, lane = tid & 63;
    const int g = lane >> 4, r = lane & 15;
    const ushort* C = ctxbf + (size_t)head * 4160;

    bf16x8 bfr[2][5];
#pragma unroll
    for (int kt = 0; kt < 2; ++kt) {
#pragma unroll
        for (int n = 0; n < 4; ++n)
            bfr[kt][n] = *(const bf16x8*)&C[(16 * n + r) * 64 + kt * 32 + 8 * g];
        bf16x8 ks = *(const bf16x8*)&C[4096 + kt * 32 + 8 * g];
        if (r != 0) {
#pragma unroll
            for (int j = 0; j < 8; ++j) ks[j] = 0;
        }
        bfr[kt][4] = ks;
    }

    const int n0 = nb * 256 + wave * 64;
    const float* qbase = Q + ((size_t)b * T_SEQ + n0) * D_MODEL + (size_t)h * 64;

    f32x4 acc[4][5];
#pragma unroll
    for (int m = 0; m < 4; ++m)
#pragma unroll
        for (int n = 0; n < 5; ++n)
#pragma unroll
            for (int q = 0; q < 4; ++q) acc[m][n][q] = 0.f;

    union U8 { unsigned u[4]; bf16x8 v; };
#pragma unroll
    for (int kt = 0; kt < 2; ++kt)
#pragma unroll
        for (int m = 0; m < 4; ++m) {
            const float* qp = qbase + (size_t)(16 * m + r) * D_MODEL + kt * 32 + 8 * g;
            const float4 q1 = *(const float4*)qp;
            const float4 q2 = *(const float4*)(qp + 4);
            U8 a;
            a.u[0] = cvt_pk_bf16(elu1(q1.x), elu1(q1.y));
            a.u[1] = cvt_pk_bf16(elu1(q1.z), elu1(q1.w));
            a.u[2] = cvt_pk_bf16(elu1(q2.x), elu1(q2.y));
            a.u[3] = cvt_pk_bf16(elu1(q2.z), elu1(q2.w));
#pragma unroll
            for (int n = 0; n < 5; ++n)
                acc[m][n] = __builtin_amdgcn_mfma_f32_16x16x32_bf16(a.v, bfr[kt][n], acc[m][n], 0, 0, 0);
        }

#pragma unroll
    for (int m = 0; m < 4; ++m) {
        float dinv[4];
#pragma unroll
        for (int q = 0; q < 4; ++q)
            dinv[q] = 1.f / (__shfl(acc[m][4][q], lane & 48) + EPS);
#pragma unroll
        for (int q = 0; q < 4; ++q) {
            float* op = out + ((size_t)b * T_SEQ + n0 + 16 * m + 4 * g + q) * D_MODEL
                        + (size_t)h * 64 + r;
#pragma unroll
            for (int n = 0; n < 4; ++n) op[16 * n] = acc[m][n][q] * dinv[q];
        }
    }
}

extern "C" void kernel_launch(void* const* d_in, const int* in_sizes, int n_in,
                              void* d_out, int out_size, void* d_ws, size_t ws_size,
                              hipStream_t stream) {
    const float* Q = (const float*)d_in[0];
    const float* K = (const float*)d_in[1];
    const float* V = (const float*)d_in[2];
    float* out = (float*)d_out;

    // Partials (64*16*4160 floats = 17 MB) live in d_out-as-scratch; consumed
    // by ctx_reduce, then d_out is fully overwritten by attn_out.
    float* partial  = out;
    ushort* ctxbf   = (ushort*)d_ws;                   // 64*4160 shorts (~0.5 MB)

    hipLaunchKernelGGL(ctx_fused,  dim3(256),  dim3(1024), 0, stream, K, V, partial);
    hipLaunchKernelGGL(ctx_reduce, dim3(256),  dim3(256),  0, stream, partial, ctxbf);
    hipLaunchKernelGGL(attn_out,   dim3(1024), dim3(256),  0, stream, Q, ctxbf, out);
}